// Round 5
// baseline (422.047 us; speedup 1.0000x reference)
//
#include <hip/hip_runtime.h>
#include <cstdint>

// ---------------------------------------------------------------------------
// JanusCrossAttention: B=2,S=2048, Q_DIM=KV_DIM=2048, H=16, D=128, KVH=4
// I/O fp32; internals bf16 MFMA, fp32 accumulate.
//   1. cvt q_stream -> bf16 sb ; transpose weights -> bf16 [N][K]
//   2. xq = sb @ wqT  (m97-style global_load_lds GEMM)
//   3. cvt kv_stream -> sb ; xkv = sb @ wkvT  (fused K|V, N=1024)
//   4. per-head RMSNorm xq, xk
//   5. repack K and V^T into MFMA-fragment-major tiles
//   6. flash attention: KVBLK=32 double-buffered LDS (32 KB/block -> 4
//      blocks/CU, 4 waves/SIMD: R4 showed 2 waves/SIMD left every pipe <50%
//      busy on dependency stalls) + XCD pinning ((b,kvh)=bid&7) + paired
//      q-tiles {31-p,p} fused into one 66-iter loop. exp2 softmax +
//      defer-max, setprio around MFMA.
//   7. out = ao @ woT (fp32 out)
// ---------------------------------------------------------------------------

using bf16 = __bf16;
using bf16x4 = __attribute__((ext_vector_type(4))) __bf16;
using bf16x8 = __attribute__((ext_vector_type(8))) __bf16;
using s16x4  = __attribute__((ext_vector_type(4))) short;
using f32x4  = __attribute__((ext_vector_type(4))) float;

#define SEQ 2048
#define NH 16
#define NKVH 4
#define HD 128

// 16x16x16 bf16 MFMA (K=16) — C layout of a prior 16x16 MFMA feeds B directly.
#if defined(__has_builtin)
#if __has_builtin(__builtin_amdgcn_mfma_f32_16x16x16bf16_1k)
#define HAVE_1K 1
#endif
#endif
__device__ __forceinline__ f32x4 mfma_16x16x16(bf16x4 a, bf16x4 b, f32x4 c) {
#ifdef HAVE_1K
    return __builtin_amdgcn_mfma_f32_16x16x16bf16_1k(
        __builtin_bit_cast(s16x4, a), __builtin_bit_cast(s16x4, b), c, 0, 0, 0);
#else
    f32x4 d;
    asm volatile("v_mfma_f32_16x16x16_bf16 %0, %1, %2, %3"
                 : "=v"(d) : "v"(a), "v"(b), "v"(c));
    return d;
#endif
}

// native exp2 (v_exp_f32)
__device__ __forceinline__ float fast_exp2(float x) {
#if defined(__has_builtin)
#if __has_builtin(__builtin_amdgcn_exp2f)
    return __builtin_amdgcn_exp2f(x);
#else
    return exp2f(x);
#endif
#else
    return exp2f(x);
#endif
}

// async global->LDS, 16B per lane. LDS dest must be wave-uniform base + lane*16.
__device__ __forceinline__ void load_lds16(const bf16* g, bf16* l) {
    __builtin_amdgcn_global_load_lds(
        (const __attribute__((address_space(1))) unsigned int*)g,
        (__attribute__((address_space(3))) unsigned int*)l, 16, 0, 0);
}

// ---------------------------------------------------------------------------
__global__ __launch_bounds__(256) void cvt_f32_bf16(const float* __restrict__ in,
                                                    bf16* __restrict__ out, int n8) {
    int i = blockIdx.x * 256 + threadIdx.x;
    if (i >= n8) return;
    const float4* p = (const float4*)in + (long)i * 2;
    float4 f0 = p[0], f1 = p[1];
    bf16x8 o = {(bf16)f0.x, (bf16)f0.y, (bf16)f0.z, (bf16)f0.w,
                (bf16)f1.x, (bf16)f1.y, (bf16)f1.z, (bf16)f1.w};
    *((bf16x8*)out + i) = o;
}

// 2D transpose + cast: in fp32 [R][C] -> out bf16 [C][R]
__global__ void transpose2d(const float* __restrict__ in, bf16* __restrict__ out,
                            int R, int C) {
    __shared__ bf16 tile[32][33];
    int x  = blockIdx.x * 32 + threadIdx.x;
    int y0 = blockIdx.y * 32 + threadIdx.y;
#pragma unroll
    for (int i = 0; i < 32; i += 8) {
        int y = y0 + i;
        if (y < R && x < C) tile[threadIdx.y + i][threadIdx.x] = (bf16)in[(long)y * C + x];
    }
    __syncthreads();
    int ox  = blockIdx.y * 32 + threadIdx.x;
    int oy0 = blockIdx.x * 32 + threadIdx.y;
#pragma unroll
    for (int i = 0; i < 32; i += 8) {
        int oy = oy0 + i;
        if (oy < C && ox < R) out[(long)oy * R + ox] = tile[threadIdx.x][threadIdx.y + i];
    }
}

// ---------------------------------------------------------------------------
// GEMM: C[M][N] = A[M][K] @ BT[N][K]^T, bf16 in, fp32 acc, CT out.
// m97 recipe: 128x128 tile, BK=32, global_load_lds width-16 staging.
template <typename CT>
__global__ __launch_bounds__(256) void gemm_bt(const bf16* __restrict__ A,
                                               const bf16* __restrict__ BT,
                                               CT* __restrict__ C,
                                               int M, int N, int K) {
    __shared__ bf16 As[128][32];
    __shared__ bf16 Bs[128][32];
    const int tid  = threadIdx.x;
    const int wave = tid >> 6, lane = tid & 63;
    const int m0 = blockIdx.y * 128, n0 = blockIdx.x * 128;
    const int wm = (wave >> 1) * 64, wn = (wave & 1) * 64;
    const int lrow = lane & 15, quad = lane >> 4;
    const int lko = quad * 8;

    const bf16* ga0 = A  + (long)(m0 + (tid >> 2)) * K + (tid & 3) * 8;
    const bf16* ga1 = ga0 + 64L * K;
    const bf16* gb0 = BT + (long)(n0 + (tid >> 2)) * K + (tid & 3) * 8;
    const bf16* gb1 = gb0 + 64L * K;
    bf16* la0 = &As[0][0] + tid * 8;
    bf16* la1 = la0 + 2048;
    bf16* lb0 = &Bs[0][0] + tid * 8;
    bf16* lb1 = lb0 + 2048;

    f32x4 acc[4][4] = {};

    for (int k0 = 0; k0 < K; k0 += 32) {
        load_lds16(ga0 + k0, la0);
        load_lds16(ga1 + k0, la1);
        load_lds16(gb0 + k0, lb0);
        load_lds16(gb1 + k0, lb1);
        __syncthreads();
        bf16x8 af[4], bfr[4];
#pragma unroll
        for (int i = 0; i < 4; ++i) af[i]  = *(const bf16x8*)(&As[wm + i * 16 + lrow][lko]);
#pragma unroll
        for (int j = 0; j < 4; ++j) bfr[j] = *(const bf16x8*)(&Bs[wn + j * 16 + lrow][lko]);
#pragma unroll
        for (int i = 0; i < 4; ++i)
#pragma unroll
            for (int j = 0; j < 4; ++j)
                acc[i][j] = __builtin_amdgcn_mfma_f32_16x16x32_bf16(af[i], bfr[j], acc[i][j], 0, 0, 0);
        __syncthreads();
    }
#pragma unroll
    for (int i = 0; i < 4; ++i) {
        int mrow0 = m0 + wm + i * 16 + quad * 4;
#pragma unroll
        for (int j = 0; j < 4; ++j) {
            int ncol = n0 + wn + j * 16 + lrow;
#pragma unroll
            for (int r = 0; r < 4; ++r)
                C[(long)(mrow0 + r) * N + ncol] = (CT)acc[i][j][r];
        }
    }
}

// ---------------------------------------------------------------------------
// Per-head RMSNorm, wave per 128-vector, in-place.
__global__ __launch_bounds__(256) void rmsnorm_head(bf16* __restrict__ X,
                                                    const float* __restrict__ W,
                                                    int nvec, int lhpr, int stride) {
    int v = blockIdx.x * 4 + (threadIdx.x >> 6);
    int lane = threadIdx.x & 63;
    if (v >= nvec) return;
    int row = v >> lhpr, head = v & ((1 << lhpr) - 1);
    bf16* x = X + (long)row * stride + head * HD;
    float fa = (float)x[lane * 2], fb = (float)x[lane * 2 + 1];
    float ss = fa * fa + fb * fb;
#pragma unroll
    for (int off = 1; off < 64; off <<= 1) ss += __shfl_xor(ss, off, 64);
    float r = rsqrtf(ss * (1.0f / 128.0f) + 1e-5f);
    x[lane * 2]     = (bf16)(fa * r * W[lane * 2]);
    x[lane * 2 + 1] = (bf16)(fb * r * W[lane * 2 + 1]);
}

// ---------------------------------------------------------------------------
// Repack K (post-RMSNorm) into fragment-major tiles:
// kf[(b*4+kvh)*32 + kt][nt(4)][ks(4)][lane(64)][8] with
//   key = kt*64 + nt*16 + (lane&15), d = ks*32 + (lane>>4)*8 + j.
// nt-major => a 32-key half-tile is a contiguous 4096-elem slice.
__global__ __launch_bounds__(256) void repack_k(const bf16* __restrict__ xkv,
                                                bf16* __restrict__ kf) {
    int kt = blockIdx.x, kvh = blockIdx.y, b = blockIdx.z;
    int tid = threadIdx.x, lane = tid & 63, ks = tid >> 6;
    int lrow = lane & 15, quad = lane >> 4;
    const bf16* src = xkv + ((long)b * SEQ + kt * 64) * 1024 + kvh * HD;
    bf16* dst = kf + ((long)((b * NKVH + kvh) * 32 + kt)) * 8192;
#pragma unroll
    for (int nt = 0; nt < 4; ++nt) {
        bf16x8 v = *(const bf16x8*)(src + (long)(nt * 16 + lrow) * 1024 + ks * 32 + quad * 8);
        *(bf16x8*)(dst + ((nt * 4 + ks) * 64 + lane) * 8) = v;
    }
}

// Repack V^T into fragment-major tiles:
// vf[(b*4+kvh)*32 + kt][nt(4)][dt(8)][lane(64)][4] with
//   d = dt*16 + (lane&15), key = kt*64 + nt*16 + (lane>>4)*4 + j.
// nt-major => a 32-key half-tile is a contiguous 4096-elem slice.
__global__ __launch_bounds__(256) void repack_v(const bf16* __restrict__ xkv,
                                                bf16* __restrict__ vf) {
    __shared__ bf16 Vls[64][136];
    int kt = blockIdx.x, kvh = blockIdx.y, b = blockIdx.z;
    int tid = threadIdx.x;
    const bf16* src = xkv + ((long)b * SEQ + kt * 64) * 1024 + 512 + kvh * HD;
#pragma unroll
    for (int p = 0; p < 4; ++p) {
        int c = p * 256 + tid;
        int r = c >> 4, dc = (c & 15) * 8;
        *(uint4*)(&Vls[r][dc]) = *(const uint4*)(src + (long)r * 1024 + dc);
    }
    __syncthreads();
    int lane = tid & 63, w = tid >> 6, lrow = lane & 15, quad = lane >> 4;
    bf16* dst = vf + ((long)((b * NKVH + kvh) * 32 + kt)) * 8192;
#pragma unroll
    for (int nt = 0; nt < 4; ++nt)
#pragma unroll
        for (int dtl = 0; dtl < 2; ++dtl) {
            int dt = w * 2 + dtl;
            bf16x4 v = {Vls[nt * 16 + quad * 4 + 0][dt * 16 + lrow],
                        Vls[nt * 16 + quad * 4 + 1][dt * 16 + lrow],
                        Vls[nt * 16 + quad * 4 + 2][dt * 16 + lrow],
                        Vls[nt * 16 + quad * 4 + 3][dt * 16 + lrow]};
            *(bf16x4*)(dst + ((nt * 8 + dt) * 64 + lane) * 4) = v;
        }
}

// ---------------------------------------------------------------------------
// Flash attention: KVBLK=32, double-buffered LDS, XCD pinning.
//
// R4 lesson: with 64-KB LDS only 2 blocks/CU fit (2 waves/SIMD) and every
// pipe sat <50% busy on dependency stalls (5550 cyc/iter vs ~1500 cyc of
// MFMA). Halving the key-block to 32 keys halves LDS to 32 KB/block ->
// 4 blocks/CU, 4 waves/SIMD, double the latency-hiding TLP. Per-work LDS
// and MFMA totals unchanged.
//
// Grid 512 1-D. Decode: (b,kvh) = bid&7 — 8 groups onto 8 XCDs via the HW's
// bid%8 round-robin; each XCD serves one group's kf/vf (1 MB) + Q slice
// (2 MB), L2-resident (R3/R4: FETCH 12.3 MB total). Staging loads are L2
// hits covered by the compute phase before the barrier's vmcnt drain.
// Block p fuses q-tiles {31-p, p} into one 66-iteration loop — every block
// does exactly 66 iterations under ANY placement.
// Softmax in exp2 domain + defer-max (T13); s_setprio(1) around MFMA (T5).
__global__ __launch_bounds__(256, 4) void attn_kernel(const bf16* __restrict__ Q,
                                                      const bf16* __restrict__ KF,
                                                      const bf16* __restrict__ VF,
                                                      bf16* __restrict__ O) {
    __shared__ bf16 Kf[2][2][4][512];   // [buf][nt][ks][lane*8] — 16 KB
    __shared__ bf16 Vf[2][2][8][256];   // [buf][nt][dt][lane*4] — 16 KB
    const int tid = threadIdx.x, wave = tid >> 6, lane = tid & 63;
    const int bid = blockIdx.x;
    const int grp = bid & 7;                  // -> XCD via bid%8 round-robin
    const int b = grp >> 2, kvh = grp & 3;
    const int slot = bid >> 3;                // 0..63
    const int pr = slot & 15;
    const int h = kvh * 4 + (slot >> 4);
    const int lrow = lane & 15, quad = lane >> 4;
    const float scl2 = 0.12751744f;     // (1/sqrt(128)) * log2(e)
    const float THR = 62.7f;            // ~8 ln-units in raw-score domain

    const int qt1 = 31 - pr, qt2 = pr;
    const int nkb1 = 2 * qt1 + 2;        // 32-key blocks for tile 1
    const int TOTAL = 66;                // nkb1 + 2*qt2+2

    const bf16* kfb = KF + ((long)(b * NKVH + kvh) * 32) * 8192;
    const bf16* vfb = VF + ((long)(b * NKVH + kvh) * 32) * 8192;

    // Q fragments for both tiles, loaded up front.
    const int myq1 = qt1 * 64 + wave * 16 + lrow;
    const int myq2 = qt2 * 64 + wave * 16 + lrow;
    const bf16* qrow1 = Q + ((long)(b * SEQ + myq1)) * (NH * HD) + h * HD;
    const bf16* qrow2 = Q + ((long)(b * SEQ + myq2)) * (NH * HD) + h * HD;
    bf16x8 bqw[4], bq2[4];
#pragma unroll
    for (int ks = 0; ks < 4; ++ks) {
        bqw[ks] = *(const bf16x8*)(qrow1 + ks * 32 + quad * 8);
        bq2[ks] = *(const bf16x8*)(qrow2 + ks * 32 + quad * 8);
    }

    // stage 32-key block kb32 into buffer bsel (K 8KB + V 8KB, 4x16B/thread)
    auto stage = [&](int kb32, int bsel) {
        const bf16* kg = kfb + (long)kb32 * 4096 + tid * 8;
        const bf16* vg = vfb + (long)kb32 * 4096 + tid * 8;
        bf16* kdst = &Kf[bsel][0][0][0] + tid * 8;
        bf16* vdst = &Vf[bsel][0][0][0] + tid * 8;
        load_lds16(kg, kdst);
        load_lds16(kg + 2048, kdst + 2048);
        load_lds16(vg, vdst);
        load_lds16(vg + 2048, vdst + 2048);
    };

    // prologue: stage kb32=0 (tile 1) into buffer 0
    stage(0, 0);
    __syncthreads();

    float m_i = -__builtin_inff(), l_i = 0.f;
    f32x4 oT[8] = {};   // out^T: d = dt*16 + quad*4 + r, q = lane&15
    int myq = myq1;

    // epilogue writer (8B stores per dt)
    auto epilogue = [&](int qrow) {
        float inv_l = 1.0f / l_i;
        bf16* obase = O + ((long)(b * SEQ + qrow)) * (NH * HD) + h * HD;
#pragma unroll
        for (int dt = 0; dt < 8; ++dt) {
            bf16x4 o = {(bf16)(oT[dt][0] * inv_l), (bf16)(oT[dt][1] * inv_l),
                        (bf16)(oT[dt][2] * inv_l), (bf16)(oT[dt][3] * inv_l)};
            *(bf16x4*)(obase + dt * 16 + quad * 4) = o;
        }
    };

#pragma unroll 1
    for (int i = 0; i < TOTAL; ++i) {
        const int cur = i & 1;
        // stage next key-block into the other buffer (released at last barrier)
        if (i + 1 < TOTAL) {
            int kbn = (i + 1 < nkb1) ? (i + 1) : (i + 1 - nkb1);
            stage(kbn, cur ^ 1);
        }
        const int kb = (i < nkb1) ? i : i - nkb1;
        // mask needed on the last TWO 32-key blocks of each tile (they cover
        // the 64-row diagonal band of the q-tile)
        const bool diag = (i >= nkb1 - 2 && i < nkb1) || (i >= TOTAL - 2);

        // S^T raw scores: key-tile nt covers keys kb*32+nt*16+quad*4+{0..3}, q=lrow
        f32x4 st[2];
        __builtin_amdgcn_s_setprio(1);
#pragma unroll
        for (int nt = 0; nt < 2; ++nt) {
            f32x4 acc = {};
#pragma unroll
            for (int ks = 0; ks < 4; ++ks) {
                bf16x8 ak = *(const bf16x8*)(&Kf[cur][nt][ks][lane * 8]);
                acc = __builtin_amdgcn_mfma_f32_16x16x32_bf16(ak, bqw[ks], acc, 0, 0, 0);
            }
            st[nt] = acc;
        }
        __builtin_amdgcn_s_setprio(0);
        if (diag) {
#pragma unroll
            for (int nt = 0; nt < 2; ++nt) {
                int kp0 = kb * 32 + nt * 16 + quad * 4;
#pragma unroll
                for (int r = 0; r < 4; ++r)
                    if (kp0 + r > myq) st[nt][r] = -__builtin_inff();
            }
        }

        // per-lane online softmax (lane owns one q row; keys spread over quads)
        float mx = st[0][0];
#pragma unroll
        for (int nt = 0; nt < 2; ++nt)
#pragma unroll
            for (int r = 0; r < 4; ++r) mx = fmaxf(mx, st[nt][r]);
        mx = fmaxf(mx, __shfl_xor(mx, 16, 64));
        mx = fmaxf(mx, __shfl_xor(mx, 32, 64));

        // defer-max: only rescale when some row's max grew past THR
        if (!__all(mx - m_i <= THR)) {
            float mnew = fmaxf(m_i, mx);
            float alpha = fast_exp2((m_i - mnew) * scl2);
            l_i *= alpha;
#pragma unroll
            for (int dt = 0; dt < 8; ++dt)
#pragma unroll
                for (int r = 0; r < 4; ++r) oT[dt][r] *= alpha;
            m_i = mnew;
        }
        float rs = 0.f;
#pragma unroll
        for (int nt = 0; nt < 2; ++nt)
#pragma unroll
            for (int r = 0; r < 4; ++r) {
                float p = fast_exp2((st[nt][r] - m_i) * scl2);
                st[nt][r] = p;
                rs += p;
            }
        rs += __shfl_xor(rs, 16, 64);
        rs += __shfl_xor(rs, 32, 64);
        l_i += rs;

        // P fragments (16x16x16 B-operand): B[n=q=lane&15][k=key=quad*4+j]
        bf16x4 pf[2];
#pragma unroll
        for (int nt = 0; nt < 2; ++nt) {
            bf16x4 tt = {(bf16)st[nt][0], (bf16)st[nt][1],
                         (bf16)st[nt][2], (bf16)st[nt][3]};
            pf[nt] = tt;
        }

        // PV: out^T += V^T · P^T, key-steps of 16; A-frag at lane*8B
        __builtin_amdgcn_s_setprio(1);
#pragma unroll
        for (int nt = 0; nt < 2; ++nt)
#pragma unroll
            for (int dt = 0; dt < 8; ++dt) {
                bf16x4 av = *(const bf16x4*)(&Vf[cur][nt][dt][lane * 4]);
                oT[dt] = mfma_16x16x16(av, pf[nt], oT[dt]);
            }
        __builtin_amdgcn_s_setprio(0);

        // seam: finish tile 1, reset softmax state, switch Q fragments
        if (i == nkb1 - 1) {
            epilogue(myq1);
            m_i = -__builtin_inff();
            l_i = 0.f;
#pragma unroll
            for (int dt = 0; dt < 8; ++dt)
#pragma unroll
                for (int r = 0; r < 4; ++r) oT[dt][r] = 0.f;
            myq = myq2;
#pragma unroll
            for (int ks = 0; ks < 4; ++ks) bqw[ks] = bq2[ks];
        }
        __syncthreads();  // release compute buffer; completes staged loads
    }

    epilogue(myq2);
}

// ---------------------------------------------------------------------------
extern "C" void kernel_launch(void* const* d_in, const int* in_sizes, int n_in,
                              void* d_out, int out_size, void* d_ws, size_t ws_size,
                              hipStream_t stream) {
    const float* q_stream  = (const float*)d_in[0];
    const float* kv_stream = (const float*)d_in[1];
    const float* wq  = (const float*)d_in[2];
    const float* wk  = (const float*)d_in[3];
    const float* wv  = (const float*)d_in[4];
    const float* wo  = (const float*)d_in[5];
    const float* qnw = (const float*)d_in[6];
    const float* knw = (const float*)d_in[7];
    float* out = (float*)d_out;

    // workspace (bf16 elems), total 30M elems = 60MB
    bf16* ws   = (bf16*)d_ws;
    bf16* sb   = ws;                        // 8M: stream buf, later attn out
    bf16* wqT  = ws + 8L * 1024 * 1024;     // 4M: wq^T, later wo^T
    bf16* wkvT = wqT + 4L * 1024 * 1024;    // 2M: [wk^T ; wv^T] = [1024][2048]
    bf16* xq   = wkvT + 2L * 1024 * 1024;   // 8M: [4096][2048]
    bf16* xkv  = xq + 8L * 1024 * 1024;     // 4M: [4096][1024] = [K | V]
    bf16* kf   = xkv + 4L * 1024 * 1024;    // 2M: K fragment-major
    bf16* vf   = kf + 2L * 1024 * 1024;     // 2M: V^T fragment-major

    dim3 tb(32, 8);
    cvt_f32_bf16<<<4096, 256, 0, stream>>>(q_stream, sb, 1048576);
    transpose2d<<<dim3(64, 64), tb, 0, stream>>>(wq, wqT, 2048, 2048);
    transpose2d<<<dim3(16, 64), tb, 0, stream>>>(wk, wkvT, 2048, 512);
    transpose2d<<<dim3(16, 64), tb, 0, stream>>>(wv, wkvT + 512L * 2048, 2048, 512);
    gemm_bt<bf16><<<dim3(16, 32), 256, 0, stream>>>(sb, wqT, xq, 4096, 2048, 2048);
    cvt_f32_bf16<<<4096, 256, 0, stream>>>(kv_stream, sb, 1048576);
    transpose2d<<<dim3(64, 64), tb, 0, stream>>>(wo, wqT, 2048, 2048);
    gemm_bt<bf16><<<dim3(8, 32), 256, 0, stream>>>(sb, wkvT, xkv, 4096, 1024, 2048);
    rmsnorm_head<<<(4096 * 16) / 4, 256, 0, stream>>>(xq, qnw, 4096 * 16, 4, 2048);
    rmsnorm_head<<<(4096 * 4) / 4, 256, 0, stream>>>(xkv, knw, 4096 * 4, 2, 1024);
    repack_k<<<dim3(32, 4, 2), 256, 0, stream>>>(xkv, kf);
    repack_v<<<dim3(32, 4, 2), 256, 0, stream>>>(xkv, vf);
    attn_kernel<<<dim3(512), 256, 0, stream>>>(xq, kf, vf, sb);
    gemm_bt<float><<<dim3(16, 32), 256, 0, stream>>>(sb, wqT, out, 4096, 2048, 2048);

    (void)in_sizes; (void)n_in; (void)out_size; (void)ws_size;
}

// Round 6
// 404.552 us; speedup vs baseline: 1.0432x; 1.0432x over previous
//
#include <hip/hip_runtime.h>
#include <cstdint>

// ---------------------------------------------------------------------------
// JanusCrossAttention: B=2,S=2048, Q_DIM=KV_DIM=2048, H=16, D=128, KVH=4
// I/O fp32; internals bf16 MFMA, fp32 accumulate.
//   1. cvt q_stream -> bf16 sb ; transpose weights -> bf16 [N][K]
//   2. xq = sb @ wqT  (m97-style global_load_lds GEMM)
//   3. cvt kv_stream -> sb ; xkv = sb @ wkvT  (fused K|V, N=1024)
//   4. per-head RMSNorm xq, xk
//   5. repack K and V^T into MFMA-fragment-major tiles
//   6. flash attention: 512-thread blocks, wave-group split-K (waves 0-3 do
//      even 32-key blocks, waves 4-7 odd; split-K softmax merge at tile end).
//      Grid 512 -> 2 blocks/CU by capacity -> 16 waves/CU (R4/R5 lesson: the
//      grid, not LDS, capped occupancy at 8 waves/CU; every pipe idled <30%
//      on dependency stalls). Paired q-tiles {31-p,p}: 33 identical
//      iterations per block under any placement. Double-buffered LDS staging,
//      XCD pinning ((b,kvh)=bid&7), exp2 softmax + defer-max, setprio.
//   7. out = ao @ woT (fp32 out)
// ---------------------------------------------------------------------------

using bf16 = __bf16;
using bf16x4 = __attribute__((ext_vector_type(4))) __bf16;
using bf16x8 = __attribute__((ext_vector_type(8))) __bf16;
using s16x4  = __attribute__((ext_vector_type(4))) short;
using f32x4  = __attribute__((ext_vector_type(4))) float;

#define SEQ 2048
#define NH 16
#define NKVH 4
#define HD 128

// finite "minus infinity": avoids inf-inf NaNs in the split-K defer-max path
#define NEG (-3.0e38f)

// 16x16x16 bf16 MFMA (K=16) — C layout of a prior 16x16 MFMA feeds B directly.
#if defined(__has_builtin)
#if __has_builtin(__builtin_amdgcn_mfma_f32_16x16x16bf16_1k)
#define HAVE_1K 1
#endif
#endif
__device__ __forceinline__ f32x4 mfma_16x16x16(bf16x4 a, bf16x4 b, f32x4 c) {
#ifdef HAVE_1K
    return __builtin_amdgcn_mfma_f32_16x16x16bf16_1k(
        __builtin_bit_cast(s16x4, a), __builtin_bit_cast(s16x4, b), c, 0, 0, 0);
#else
    f32x4 d;
    asm volatile("v_mfma_f32_16x16x16_bf16 %0, %1, %2, %3"
                 : "=v"(d) : "v"(a), "v"(b), "v"(c));
    return d;
#endif
}

// native exp2 (v_exp_f32)
__device__ __forceinline__ float fast_exp2(float x) {
#if defined(__has_builtin)
#if __has_builtin(__builtin_amdgcn_exp2f)
    return __builtin_amdgcn_exp2f(x);
#else
    return exp2f(x);
#endif
#else
    return exp2f(x);
#endif
}

// async global->LDS, 16B per lane. LDS dest must be wave-uniform base + lane*16.
__device__ __forceinline__ void load_lds16(const bf16* g, bf16* l) {
    __builtin_amdgcn_global_load_lds(
        (const __attribute__((address_space(1))) unsigned int*)g,
        (__attribute__((address_space(3))) unsigned int*)l, 16, 0, 0);
}

// ---------------------------------------------------------------------------
__global__ __launch_bounds__(256) void cvt_f32_bf16(const float* __restrict__ in,
                                                    bf16* __restrict__ out, int n8) {
    int i = blockIdx.x * 256 + threadIdx.x;
    if (i >= n8) return;
    const float4* p = (const float4*)in + (long)i * 2;
    float4 f0 = p[0], f1 = p[1];
    bf16x8 o = {(bf16)f0.x, (bf16)f0.y, (bf16)f0.z, (bf16)f0.w,
                (bf16)f1.x, (bf16)f1.y, (bf16)f1.z, (bf16)f1.w};
    *((bf16x8*)out + i) = o;
}

// 2D transpose + cast: in fp32 [R][C] -> out bf16 [C][R]
__global__ void transpose2d(const float* __restrict__ in, bf16* __restrict__ out,
                            int R, int C) {
    __shared__ bf16 tile[32][33];
    int x  = blockIdx.x * 32 + threadIdx.x;
    int y0 = blockIdx.y * 32 + threadIdx.y;
#pragma unroll
    for (int i = 0; i < 32; i += 8) {
        int y = y0 + i;
        if (y < R && x < C) tile[threadIdx.y + i][threadIdx.x] = (bf16)in[(long)y * C + x];
    }
    __syncthreads();
    int ox  = blockIdx.y * 32 + threadIdx.x;
    int oy0 = blockIdx.x * 32 + threadIdx.y;
#pragma unroll
    for (int i = 0; i < 32; i += 8) {
        int oy = oy0 + i;
        if (oy < C && ox < R) out[(long)oy * R + ox] = tile[threadIdx.x][threadIdx.y + i];
    }
}

// ---------------------------------------------------------------------------
// GEMM: C[M][N] = A[M][K] @ BT[N][K]^T, bf16 in, fp32 acc, CT out.
// m97 recipe: 128x128 tile, BK=32, global_load_lds width-16 staging.
template <typename CT>
__global__ __launch_bounds__(256) void gemm_bt(const bf16* __restrict__ A,
                                               const bf16* __restrict__ BT,
                                               CT* __restrict__ C,
                                               int M, int N, int K) {
    __shared__ bf16 As[128][32];
    __shared__ bf16 Bs[128][32];
    const int tid  = threadIdx.x;
    const int wave = tid >> 6, lane = tid & 63;
    const int m0 = blockIdx.y * 128, n0 = blockIdx.x * 128;
    const int wm = (wave >> 1) * 64, wn = (wave & 1) * 64;
    const int lrow = lane & 15, quad = lane >> 4;
    const int lko = quad * 8;

    const bf16* ga0 = A  + (long)(m0 + (tid >> 2)) * K + (tid & 3) * 8;
    const bf16* ga1 = ga0 + 64L * K;
    const bf16* gb0 = BT + (long)(n0 + (tid >> 2)) * K + (tid & 3) * 8;
    const bf16* gb1 = gb0 + 64L * K;
    bf16* la0 = &As[0][0] + tid * 8;
    bf16* la1 = la0 + 2048;
    bf16* lb0 = &Bs[0][0] + tid * 8;
    bf16* lb1 = lb0 + 2048;

    f32x4 acc[4][4] = {};

    for (int k0 = 0; k0 < K; k0 += 32) {
        load_lds16(ga0 + k0, la0);
        load_lds16(ga1 + k0, la1);
        load_lds16(gb0 + k0, lb0);
        load_lds16(gb1 + k0, lb1);
        __syncthreads();
        bf16x8 af[4], bfr[4];
#pragma unroll
        for (int i = 0; i < 4; ++i) af[i]  = *(const bf16x8*)(&As[wm + i * 16 + lrow][lko]);
#pragma unroll
        for (int j = 0; j < 4; ++j) bfr[j] = *(const bf16x8*)(&Bs[wn + j * 16 + lrow][lko]);
#pragma unroll
        for (int i = 0; i < 4; ++i)
#pragma unroll
            for (int j = 0; j < 4; ++j)
                acc[i][j] = __builtin_amdgcn_mfma_f32_16x16x32_bf16(af[i], bfr[j], acc[i][j], 0, 0, 0);
        __syncthreads();
    }
#pragma unroll
    for (int i = 0; i < 4; ++i) {
        int mrow0 = m0 + wm + i * 16 + quad * 4;
#pragma unroll
        for (int j = 0; j < 4; ++j) {
            int ncol = n0 + wn + j * 16 + lrow;
#pragma unroll
            for (int r = 0; r < 4; ++r)
                C[(long)(mrow0 + r) * N + ncol] = (CT)acc[i][j][r];
        }
    }
}

// ---------------------------------------------------------------------------
// Per-head RMSNorm, wave per 128-vector, in-place.
__global__ __launch_bounds__(256) void rmsnorm_head(bf16* __restrict__ X,
                                                    const float* __restrict__ W,
                                                    int nvec, int lhpr, int stride) {
    int v = blockIdx.x * 4 + (threadIdx.x >> 6);
    int lane = threadIdx.x & 63;
    if (v >= nvec) return;
    int row = v >> lhpr, head = v & ((1 << lhpr) - 1);
    bf16* x = X + (long)row * stride + head * HD;
    float fa = (float)x[lane * 2], fb = (float)x[lane * 2 + 1];
    float ss = fa * fa + fb * fb;
#pragma unroll
    for (int off = 1; off < 64; off <<= 1) ss += __shfl_xor(ss, off, 64);
    float r = rsqrtf(ss * (1.0f / 128.0f) + 1e-5f);
    x[lane * 2]     = (bf16)(fa * r * W[lane * 2]);
    x[lane * 2 + 1] = (bf16)(fb * r * W[lane * 2 + 1]);
}

// ---------------------------------------------------------------------------
// Repack K (post-RMSNorm) into fragment-major tiles:
// kf[(b*4+kvh)*32 + kt][nt(4)][ks(4)][lane(64)][8] with
//   key = kt*64 + nt*16 + (lane&15), d = ks*32 + (lane>>4)*8 + j.
// nt-major => a 32-key half-tile is a contiguous 4096-elem slice.
__global__ __launch_bounds__(256) void repack_k(const bf16* __restrict__ xkv,
                                                bf16* __restrict__ kf) {
    int kt = blockIdx.x, kvh = blockIdx.y, b = blockIdx.z;
    int tid = threadIdx.x, lane = tid & 63, ks = tid >> 6;
    int lrow = lane & 15, quad = lane >> 4;
    const bf16* src = xkv + ((long)b * SEQ + kt * 64) * 1024 + kvh * HD;
    bf16* dst = kf + ((long)((b * NKVH + kvh) * 32 + kt)) * 8192;
#pragma unroll
    for (int nt = 0; nt < 4; ++nt) {
        bf16x8 v = *(const bf16x8*)(src + (long)(nt * 16 + lrow) * 1024 + ks * 32 + quad * 8);
        *(bf16x8*)(dst + ((nt * 4 + ks) * 64 + lane) * 8) = v;
    }
}

// Repack V^T into fragment-major tiles:
// vf[(b*4+kvh)*32 + kt][nt(4)][dt(8)][lane(64)][4] with
//   d = dt*16 + (lane&15), key = kt*64 + nt*16 + (lane>>4)*4 + j.
// nt-major => a 32-key half-tile is a contiguous 4096-elem slice.
__global__ __launch_bounds__(256) void repack_v(const bf16* __restrict__ xkv,
                                                bf16* __restrict__ vf) {
    __shared__ bf16 Vls[64][136];
    int kt = blockIdx.x, kvh = blockIdx.y, b = blockIdx.z;
    int tid = threadIdx.x;
    const bf16* src = xkv + ((long)b * SEQ + kt * 64) * 1024 + 512 + kvh * HD;
#pragma unroll
    for (int p = 0; p < 4; ++p) {
        int c = p * 256 + tid;
        int r = c >> 4, dc = (c & 15) * 8;
        *(uint4*)(&Vls[r][dc]) = *(const uint4*)(src + (long)r * 1024 + dc);
    }
    __syncthreads();
    int lane = tid & 63, w = tid >> 6, lrow = lane & 15, quad = lane >> 4;
    bf16* dst = vf + ((long)((b * NKVH + kvh) * 32 + kt)) * 8192;
#pragma unroll
    for (int nt = 0; nt < 4; ++nt)
#pragma unroll
        for (int dtl = 0; dtl < 2; ++dtl) {
            int dt = w * 2 + dtl;
            bf16x4 v = {Vls[nt * 16 + quad * 4 + 0][dt * 16 + lrow],
                        Vls[nt * 16 + quad * 4 + 1][dt * 16 + lrow],
                        Vls[nt * 16 + quad * 4 + 2][dt * 16 + lrow],
                        Vls[nt * 16 + quad * 4 + 3][dt * 16 + lrow]};
            *(bf16x4*)(dst + ((nt * 8 + dt) * 64 + lane) * 4) = v;
        }
}

// ---------------------------------------------------------------------------
// Flash attention: 512-thread blocks, wave-group split-K.
//
// Waves 0-3 (group 0) process even 32-key blocks, waves 4-7 (group 1) odd,
// over the SAME 64 q-rows; each group keeps its own (m,l,oT). Per 64-key
// staged pair both groups work every iteration (nkb=2(qt+1) is even -> no
// idle). At tile end a 2-phase LDS combine merges group 1 into group 0:
//   m* = max(m0,m1); a_g = 2^((m_g-m*)*scl2); l* = a0 l0 + a1 l1;
//   oT* = a0 oT0 + a1 oT1.
// Grid 512, 2 blocks/CU by capacity (LDS 64KB, VGPR<=128) -> 16 waves/CU =
// 4 waves/SIMD (R4/R5: grid capped us at 2 waves/SIMD; all pipes <30% busy).
// XCD pinning: (b,kvh) = bid&7 -> one group's 1MB K/V per XCD L2 (R3/R4:
// FETCH 12.3 MB). Paired q-tiles {31-p,p}: it1+it2 = 33 for every block.
// Sentinel NEG (-3e38) not -inf: group 1 starts at keys 32.. so tile qt=0
// has fully-masked rows; -inf would NaN through the defer-max check.
__global__ __launch_bounds__(512, 4) void attn_kernel(const bf16* __restrict__ Q,
                                                      const bf16* __restrict__ KF,
                                                      const bf16* __restrict__ VF,
                                                      bf16* __restrict__ O) {
    __shared__ bf16 Kf[2][8192];   // [buf][half(2)·nt(2)·ks(4)·512] — 32 KB
    __shared__ bf16 Vf[2][8192];   // [buf][half(2)·nt(2)·dt(8)·256] — 32 KB
    const int tid = threadIdx.x, wave = tid >> 6, lane = tid & 63;
    const int w4 = wave & 3, grpW = wave >> 2;
    const int bid = blockIdx.x;
    const int grp = bid & 7;                  // -> XCD via bid%8 round-robin
    const int b = grp >> 2, kvh = grp & 3;
    const int slot = bid >> 3;                // 0..63
    const int pr = slot & 15;
    const int h = kvh * 4 + (slot >> 4);
    const int lrow = lane & 15, quad = lane >> 4;
    const float scl2 = 0.12751744f;     // (1/sqrt(128)) * log2(e)
    const float THR = 62.7f;            // ~8 ln-units in raw-score domain

    const int qt1 = 31 - pr, qt2 = pr;

    const bf16* kfb = KF + ((long)(b * NKVH + kvh) * 32) * 8192;
    const bf16* vfb = VF + ((long)(b * NKVH + kvh) * 32) * 8192;

    // stage 64-key pair (== repack tile) into buffer bsel: 512thr x 2x16B each
    auto stage = [&](int pair, int bsel) {
        const bf16* kg = kfb + (long)pair * 8192 + tid * 8;
        const bf16* vg = vfb + (long)pair * 8192 + tid * 8;
        bf16* kd = &Kf[bsel][0] + tid * 8;
        bf16* vd = &Vf[bsel][0] + tid * 8;
        load_lds16(kg, kd);
        load_lds16(kg + 4096, kd + 4096);
        load_lds16(vg, vd);
        load_lds16(vg + 4096, vd + 4096);
    };

    float m_i = NEG, l_i = 0.f;
    f32x4 oT[8] = {};   // out^T: d = dt*16 + quad*4 + r, q = lane&15
    bf16x8 bqw[4];

    // split-K combine (group1 -> group0 via Vf scratch) + output write + reset
    auto combine_write_reset = [&](int qrow) {
        float a1keep = 0.f;
        float* vs = (float*)&Vf[0][0];
        const int sl = w4 * 64 + lane;
        __syncthreads();
        if (grpW == 1) {
            float* d = vs + sl * 18;
#pragma unroll
            for (int dt = 0; dt < 4; ++dt)
#pragma unroll
                for (int r = 0; r < 4; ++r) d[dt * 4 + r] = oT[dt][r];
            d[16] = m_i; d[17] = l_i;
        }
        __syncthreads();
        if (grpW == 0) {
            const float* s = vs + sl * 18;
            float m1 = s[16], l1 = s[17];
            float ms = fmaxf(m_i, m1);
            float a0 = fast_exp2((m_i - ms) * scl2);
            float a1 = fast_exp2((m1 - ms) * scl2);
            a1keep = a1;
            l_i = a0 * l_i + a1 * l1;
#pragma unroll
            for (int dt = 0; dt < 4; ++dt)
#pragma unroll
                for (int r = 0; r < 4; ++r)
                    oT[dt][r] = a0 * oT[dt][r] + a1 * s[dt * 4 + r];
#pragma unroll
            for (int dt = 4; dt < 8; ++dt)
#pragma unroll
                for (int r = 0; r < 4; ++r) oT[dt][r] *= a0;
            m_i = ms;
        }
        __syncthreads();
        if (grpW == 1) {
            float* d = vs + sl * 16;
#pragma unroll
            for (int dt = 4; dt < 8; ++dt)
#pragma unroll
                for (int r = 0; r < 4; ++r) d[(dt - 4) * 4 + r] = oT[dt][r];
        }
        __syncthreads();
        if (grpW == 0) {
            const float* s = vs + sl * 16;
#pragma unroll
            for (int dt = 4; dt < 8; ++dt)
#pragma unroll
                for (int r = 0; r < 4; ++r) oT[dt][r] += a1keep * s[(dt - 4) * 4 + r];
            float inv_l = 1.0f / l_i;
            bf16* obase = O + ((long)(b * SEQ + qrow)) * (NH * HD) + h * HD;
#pragma unroll
            for (int dt = 0; dt < 8; ++dt) {
                bf16x4 o = {(bf16)(oT[dt][0] * inv_l), (bf16)(oT[dt][1] * inv_l),
                            (bf16)(oT[dt][2] * inv_l), (bf16)(oT[dt][3] * inv_l)};
                *(bf16x4*)(obase + dt * 16 + quad * 4) = o;
            }
        }
        __syncthreads();   // scratch/LDS free for restage
        m_i = NEG; l_i = 0.f;
#pragma unroll
        for (int dt = 0; dt < 8; ++dt)
#pragma unroll
            for (int r = 0; r < 4; ++r) oT[dt][r] = 0.f;
    };

    // process the current staged pair: group's 32-key block kbg
    auto process = [&](int i, int itN, int myq, int cur) {
        const int kbg = 2 * i + grpW;
        const bool diag = (i == itN - 1);
        const bf16* kbase = &Kf[cur][0] + grpW * 4096;
        const bf16* vbase = &Vf[cur][0] + grpW * 4096;

        f32x4 st[2];
        __builtin_amdgcn_s_setprio(1);
#pragma unroll
        for (int nt = 0; nt < 2; ++nt) {
            f32x4 acc = {};
#pragma unroll
            for (int ks = 0; ks < 4; ++ks) {
                bf16x8 ak = *(const bf16x8*)(kbase + (nt * 4 + ks) * 512 + lane * 8);
                acc = __builtin_amdgcn_mfma_f32_16x16x32_bf16(ak, bqw[ks], acc, 0, 0, 0);
            }
            st[nt] = acc;
        }
        __builtin_amdgcn_s_setprio(0);
        if (diag) {
#pragma unroll
            for (int nt = 0; nt < 2; ++nt) {
                int kp0 = kbg * 32 + nt * 16 + quad * 4;
#pragma unroll
                for (int r = 0; r < 4; ++r)
                    if (kp0 + r > myq) st[nt][r] = NEG;
            }
        }

        float mx = st[0][0];
#pragma unroll
        for (int nt = 0; nt < 2; ++nt)
#pragma unroll
            for (int r = 0; r < 4; ++r) mx = fmaxf(mx, st[nt][r]);
        mx = fmaxf(mx, __shfl_xor(mx, 16, 64));
        mx = fmaxf(mx, __shfl_xor(mx, 32, 64));

        if (!__all(mx - m_i <= THR)) {
            float mnew = fmaxf(m_i, mx);
            float alpha = fast_exp2((m_i - mnew) * scl2);
            l_i *= alpha;
#pragma unroll
            for (int dt = 0; dt < 8; ++dt)
#pragma unroll
                for (int r = 0; r < 4; ++r) oT[dt][r] *= alpha;
            m_i = mnew;
        }
        float rs = 0.f;
#pragma unroll
        for (int nt = 0; nt < 2; ++nt)
#pragma unroll
            for (int r = 0; r < 4; ++r) {
                float p = fast_exp2((st[nt][r] - m_i) * scl2);
                st[nt][r] = p;
                rs += p;
            }
        rs += __shfl_xor(rs, 16, 64);
        rs += __shfl_xor(rs, 32, 64);
        l_i += rs;

        bf16x4 pf[2];
#pragma unroll
        for (int nt = 0; nt < 2; ++nt) {
            bf16x4 tt = {(bf16)st[nt][0], (bf16)st[nt][1],
                         (bf16)st[nt][2], (bf16)st[nt][3]};
            pf[nt] = tt;
        }

        __builtin_amdgcn_s_setprio(1);
#pragma unroll
        for (int nt = 0; nt < 2; ++nt)
#pragma unroll
            for (int dt = 0; dt < 8; ++dt) {
                bf16x4 av = *(const bf16x4*)(vbase + (nt * 8 + dt) * 256 + lane * 4);
                oT[dt] = mfma_16x16x16(av, pf[nt], oT[dt]);
            }
        __builtin_amdgcn_s_setprio(0);
    };

    // ---- tile 1: qt1, it1 = qt1+1 staged pairs --------------------------
    const int it1 = qt1 + 1;
    const int myq1 = qt1 * 64 + w4 * 16 + lrow;
    {
        const bf16* qrow = Q + ((long)(b * SEQ + myq1)) * (NH * HD) + h * HD;
#pragma unroll
        for (int ks = 0; ks < 4; ++ks)
            bqw[ks] = *(const bf16x8*)(qrow + ks * 32 + quad * 8);
    }
    stage(0, 0);
    __syncthreads();
#pragma unroll 1
    for (int i = 0; i < it1; ++i) {
        const int cur = i & 1;
        if (i + 1 < it1) stage(i + 1, cur ^ 1);   // seam: no prefetch (combine scribbles Vf)
        process(i, it1, myq1, cur);
        __syncthreads();
    }
    combine_write_reset(myq1);

    // ---- tile 2: qt2, it2 = qt2+1 staged pairs --------------------------
    const int it2 = qt2 + 1;
    const int myq2 = qt2 * 64 + w4 * 16 + lrow;
    {
        const bf16* qrow = Q + ((long)(b * SEQ + myq2)) * (NH * HD) + h * HD;
#pragma unroll
        for (int ks = 0; ks < 4; ++ks)
            bqw[ks] = *(const bf16x8*)(qrow + ks * 32 + quad * 8);
    }
    stage(0, 0);
    __syncthreads();
#pragma unroll 1
    for (int i = 0; i < it2; ++i) {
        const int cur = i & 1;
        if (i + 1 < it2) stage(i + 1, cur ^ 1);
        process(i, it2, myq2, cur);
        __syncthreads();
    }
    combine_write_reset(myq2);
}

// ---------------------------------------------------------------------------
extern "C" void kernel_launch(void* const* d_in, const int* in_sizes, int n_in,
                              void* d_out, int out_size, void* d_ws, size_t ws_size,
                              hipStream_t stream) {
    const float* q_stream  = (const float*)d_in[0];
    const float* kv_stream = (const float*)d_in[1];
    const float* wq  = (const float*)d_in[2];
    const float* wk  = (const float*)d_in[3];
    const float* wv  = (const float*)d_in[4];
    const float* wo  = (const float*)d_in[5];
    const float* qnw = (const float*)d_in[6];
    const float* knw = (const float*)d_in[7];
    float* out = (float*)d_out;

    // workspace (bf16 elems), total 30M elems = 60MB
    bf16* ws   = (bf16*)d_ws;
    bf16* sb   = ws;                        // 8M: stream buf, later attn out
    bf16* wqT  = ws + 8L * 1024 * 1024;     // 4M: wq^T, later wo^T
    bf16* wkvT = wqT + 4L * 1024 * 1024;    // 2M: [wk^T ; wv^T] = [1024][2048]
    bf16* xq   = wkvT + 2L * 1024 * 1024;   // 8M: [4096][2048]
    bf16* xkv  = xq + 8L * 1024 * 1024;     // 4M: [4096][1024] = [K | V]
    bf16* kf   = xkv + 4L * 1024 * 1024;    // 2M: K fragment-major
    bf16* vf   = kf + 2L * 1024 * 1024;     // 2M: V^T fragment-major

    dim3 tb(32, 8);
    cvt_f32_bf16<<<4096, 256, 0, stream>>>(q_stream, sb, 1048576);
    transpose2d<<<dim3(64, 64), tb, 0, stream>>>(wq, wqT, 2048, 2048);
    transpose2d<<<dim3(16, 64), tb, 0, stream>>>(wk, wkvT, 2048, 512);
    transpose2d<<<dim3(16, 64), tb, 0, stream>>>(wv, wkvT + 512L * 2048, 2048, 512);
    gemm_bt<bf16><<<dim3(16, 32), 256, 0, stream>>>(sb, wqT, xq, 4096, 2048, 2048);
    cvt_f32_bf16<<<4096, 256, 0, stream>>>(kv_stream, sb, 1048576);
    transpose2d<<<dim3(64, 64), tb, 0, stream>>>(wo, wqT, 2048, 2048);
    gemm_bt<bf16><<<dim3(8, 32), 256, 0, stream>>>(sb, wkvT, xkv, 4096, 1024, 2048);
    rmsnorm_head<<<(4096 * 16) / 4, 256, 0, stream>>>(xq, qnw, 4096 * 16, 4, 2048);
    rmsnorm_head<<<(4096 * 4) / 4, 256, 0, stream>>>(xkv, knw, 4096 * 4, 2, 1024);
    repack_k<<<dim3(32, 4, 2), 256, 0, stream>>>(xkv, kf);
    repack_v<<<dim3(32, 4, 2), 256, 0, stream>>>(xkv, vf);
    attn_kernel<<<dim3(512), dim3(512), 0, stream>>>(xq, kf, vf, sb);
    gemm_bt<float><<<dim3(16, 32), 256, 0, stream>>>(sb, wqT, out, 4096, 2048, 2048);

    (void)in_sizes; (void)n_in; (void)out_size; (void)ws_size;
}